// Round 2
// baseline (844.593 us; speedup 1.0000x reference)
//
#include <hip/hip_runtime.h>
#include <math.h>

#define B_ 32
#define L_ 4096
#define D_ 1024
#define A_ 8
#define CHUNK 256
#define NSB 7

// ---------------------------------------------------------------------------
// Kernel 1: masked segmented sum of embeddings into per-(b,action) buckets.
// grid = B * (L/CHUNK) blocks, 256 threads. Thread t owns dims [4t, 4t+3].
// Action index per position is block-uniform -> readfirstlane + scalar switch.
// NOTE: mask arrives as int32 (harness promotes bool -> int32).
// ---------------------------------------------------------------------------
__global__ __launch_bounds__(256) void k_accum(
    const float* __restrict__ emb, const int* __restrict__ actions,
    const int* __restrict__ mask,
    float* __restrict__ sums /*B*A*D*/, float* __restrict__ counts /*B*A*/)
{
  const int chunks_per_b = L_ / CHUNK;
  const int b  = blockIdx.x / chunks_per_b;
  const int l0 = (blockIdx.x % chunks_per_b) * CHUNK;
  const int t  = threadIdx.x;

  __shared__ int s_act[CHUNK];
  for (int i = t; i < CHUNK; i += 256) {
    const int idx = b * L_ + l0 + i;
    const int a = actions[idx];
    s_act[i] = (mask[idx] != 0) ? a : -1;
  }
  __syncthreads();

  // per-block action counts (threads 0..7)
  if (t < A_) {
    int cnt = 0;
    for (int i = 0; i < CHUNK; ++i) cnt += (s_act[i] == t) ? 1 : 0;
    if (cnt) atomicAdd(&counts[b * A_ + t], (float)cnt);
  }

  float4 acc[A_];
#pragma unroll
  for (int j = 0; j < A_; ++j) acc[j] = make_float4(0.f, 0.f, 0.f, 0.f);

  const float4* __restrict__ row =
      (const float4*)(emb + (size_t)(b * L_ + l0) * D_);

#define ADD4(J, V) \
  acc[J].x += (V).x; acc[J].y += (V).y; acc[J].z += (V).z; acc[J].w += (V).w

#pragma unroll 1
  for (int i = 0; i < CHUNK; i += 8) {
    float4 v[8];
#pragma unroll
    for (int u = 0; u < 8; ++u) v[u] = row[(size_t)(i + u) * (D_ / 4) + t];
#pragma unroll
    for (int u = 0; u < 8; ++u) {
      const int a = __builtin_amdgcn_readfirstlane(s_act[i + u]);
      switch (a) {
        case 0: ADD4(0, v[u]); break;
        case 1: ADD4(1, v[u]); break;
        case 2: ADD4(2, v[u]); break;
        case 3: ADD4(3, v[u]); break;
        case 4: ADD4(4, v[u]); break;
        case 5: ADD4(5, v[u]); break;
        case 6: ADD4(6, v[u]); break;
        case 7: ADD4(7, v[u]); break;
        default: break;
      }
    }
  }
#undef ADD4

  float* __restrict__ dst = sums + (size_t)b * A_ * D_;
#pragma unroll
  for (int j = 0; j < A_; ++j) {
    float* p = dst + j * D_ + 4 * t;
    atomicAdd(p + 0, acc[j].x);
    atomicAdd(p + 1, acc[j].y);
    atomicAdd(p + 2, acc[j].z);
    atomicAdd(p + 3, acc[j].w);
  }
}

// ---------------------------------------------------------------------------
// Kernel 2: feats = sums/clip(counts,1); two tiny MLP heads + epilogues.
// grid = B*A blocks (one (b,a) row each), 256 threads.
// ---------------------------------------------------------------------------
__global__ __launch_bounds__(256) void k_head(
    const float* __restrict__ sums, const float* __restrict__ counts,
    const float* __restrict__ sw1, const float* __restrict__ sb1,
    const float* __restrict__ sw2, const float* __restrict__ sb2,
    const float* __restrict__ ew1, const float* __restrict__ eb1,
    const float* __restrict__ ew2, const float* __restrict__ eb2,
    float* __restrict__ out)
{
  const int ba = blockIdx.x;   // b*A + a
  const int t  = threadIdx.x;

  __shared__ float s_feat[D_];
  __shared__ float s_h1[128];
  __shared__ float s_he[64];
  __shared__ float s_logits[2 * NSB];
  __shared__ float s_eff[3];

  const float cnt = counts[ba];
  const float inv = 1.0f / fmaxf(cnt, 1.0f);
  for (int d = t; d < D_; d += 256) s_feat[d] = sums[(size_t)ba * D_ + d] * inv;
  __syncthreads();

  if (t < 128) {
    float acc = sb1[t];
#pragma unroll 4
    for (int d = 0; d < D_; ++d) acc += s_feat[d] * sw1[d * 128 + t];
    s_h1[t] = fmaxf(acc, 0.f);
  } else if (t < 192) {
    const int j = t - 128;
    float acc = eb1[j];
#pragma unroll 4
    for (int d = 0; d < D_; ++d) acc += s_feat[d] * ew1[d * 64 + j];
    s_he[j] = fmaxf(acc, 0.f);
  }
  __syncthreads();

  if (t < 2 * NSB) {
    float acc = sb2[t];
#pragma unroll 4
    for (int k = 0; k < 128; ++k) acc += s_h1[k] * sw2[k * (2 * NSB) + t];
    s_logits[t] = acc;
  } else if (t < 2 * NSB + 3) {
    const int j = t - 2 * NSB;
    float acc = eb2[j];
#pragma unroll 4
    for (int k = 0; k < 64; ++k) acc += s_he[k] * ew2[k * 3 + j];
    s_eff[j] = acc;
  }
  __syncthreads();

  const float seen = (cnt > 0.f) ? 1.f : 0.f;

  float* __restrict__ out0 = out;                 // (B,A,2)   512
  float* __restrict__ out1 = out + 512;           // (B,A,7)  1792
  float* __restrict__ out2 = out + 2304;          // (B,A,7)  1792
  float* __restrict__ out3 = out + 4096;          // (B,A)     256
  float* __restrict__ out4 = out + 4352;          // (B,A)     256
  float* __restrict__ out5 = out + 4608;          // (B,A)     256

  if (t < NSB) {
    out1[ba * NSB + t] = s_logits[t];
    out2[ba * NSB + t] = s_logits[NSB + t];
  }

  if (t == 0) {
    const float bins[NSB] = {-16.f, -8.f, -4.f, 0.f, 4.f, 8.f, 16.f};
    float dxy[2];
#pragma unroll
    for (int h = 0; h < 2; ++h) {
      const float* lg = &s_logits[h * NSB];
      float m = lg[0];
      for (int i = 1; i < NSB; ++i) m = fmaxf(m, lg[i]);
      float s = 0.f, acc = 0.f;
      for (int i = 0; i < NSB; ++i) {
        const float e = expf(lg[i] - m);
        s += e;
        acc += e * bins[i];
      }
      dxy[h] = acc / s;
    }
    out0[ba * 2 + 0] = dxy[0] * seen;
    out0[ba * 2 + 1] = dxy[1] * seen;
    out3[ba] = (1.f / (1.f + expf(-s_eff[0]))) * seen;
    out4[ba] = (1.f / (1.f + expf(-s_eff[1]))) * seen;
    out5[ba] = s_eff[2] * seen;
  }
}

extern "C" void kernel_launch(void* const* d_in, const int* in_sizes, int n_in,
                              void* d_out, int out_size, void* d_ws, size_t ws_size,
                              hipStream_t stream) {
  const float* emb     = (const float*)d_in[0];
  const int*   actions = (const int*)d_in[1];
  const int*   mask    = (const int*)d_in[2];
  const float* sw1 = (const float*)d_in[3];
  const float* sb1 = (const float*)d_in[4];
  const float* sw2 = (const float*)d_in[5];
  const float* sb2 = (const float*)d_in[6];
  const float* ew1 = (const float*)d_in[7];
  const float* eb1 = (const float*)d_in[8];
  const float* ew2 = (const float*)d_in[9];
  const float* eb2 = (const float*)d_in[10];
  float* out = (float*)d_out;

  float* sums   = (float*)d_ws;            // B*A*D floats = 1 MiB
  float* counts = sums + B_ * A_ * D_;     // B*A floats

  hipMemsetAsync(d_ws, 0, (size_t)(B_ * A_ * D_ + B_ * A_) * sizeof(float),
                 stream);

  hipLaunchKernelGGL(k_accum, dim3(B_ * (L_ / CHUNK)), dim3(256), 0, stream,
                     emb, actions, mask, sums, counts);
  hipLaunchKernelGGL(k_head, dim3(B_ * A_), dim3(256), 0, stream,
                     sums, counts, sw1, sb1, sw2, sb2, ew1, eb1, ew2, eb2, out);
}